// Round 5
// baseline (227.181 us; speedup 1.0000x reference)
//
#include <hip/hip_runtime.h>

#define N_NODES 100000
#define D_INF   128
#define D_HID   256
#define K_CL    16
#define N_TILES (N_NODES / 16)       // 6250, exact
#define N_EDGES 3200000
#define EDGE_BLOCKS (N_EDGES / 1024) // 3125: 4 waves x 256 edges

typedef __attribute__((ext_vector_type(8))) __bf16  bf16x8;
typedef __attribute__((ext_vector_type(8))) unsigned short u16x8;
typedef __attribute__((ext_vector_type(4))) float   f32x4;
typedef __attribute__((ext_vector_type(2))) float   f32x2;
typedef __attribute__((ext_vector_type(4))) unsigned int u32x4;

__device__ __forceinline__ unsigned short f2bf(float f) {
    unsigned int u = __builtin_bit_cast(unsigned int, f);
    u += 0x7fffu + ((u >> 16) & 1u);          // RNE
    return (unsigned short)(u >> 16);
}

// ---------------------------------------------------------------------------
// Fused MLP, now also absorbing the old prep kernel (R5: 4 kernels -> 2).
// Each block converts W1 f32 -> bf16 straight into its LDS tile (coalesced
// f32 reads, packed b32 LDS writes; ~0.5us one-time, identical f2bf values
// so output is bit-identical to the prep-kernel version). W2/b2 convert
// into registers. Removes the prep kernel + its graph-node gap and the
// w1t/w2t global round-trip.
// Core loop is R2-verbatim: MFMA 16x16x32 bf16, 4 waves/block, wave = one
// 16-node tile, x prefetch one tile ahead, fp8 e4m3 loss-path copy (R4).
// ---------------------------------------------------------------------------
#define W1S 136      // LDS row stride (bf16) for W1T
#define CHS 40       // LDS row stride (bf16) for h chunk

__global__ __launch_bounds__(256, 2) void mlp_kernel(
    const float* __restrict__ x, const float* __restrict__ W1,
    const float* __restrict__ b1, const float* __restrict__ W2,
    const float* __restrict__ b2, float* __restrict__ C,
    unsigned char* __restrict__ C8, unsigned int* __restrict__ ticket)
{
    __shared__ unsigned short w1s[256 * W1S];          // 69,632 B
    __shared__ unsigned short chbuf[4][2][16 * CHS];   // 10,240 B
    __shared__ float b1s[D_HID];                       //  1,024 B -> 80,896

    const int tid  = threadIdx.x;
    const int wv   = tid >> 6;
    const int lane = tid & 63;
    const int c    = lane & 15;
    const int q    = lane >> 4;

    // ---- zero the edge ticket (ws is poison-filled each iteration;
    //      agent-scope store so the edge kernel's LLC atomic sees it) ----
    if (blockIdx.x == 0 && tid == 0)
        __hip_atomic_store(ticket, 0u, __ATOMIC_RELAXED,
                           __HIP_MEMORY_SCOPE_AGENT);

    // ---- stage W1 [k=128][n=256] f32 -> w1s[n][k] bf16 (transposed) ----
    // loads coalesced across tid (=n); packed pairs -> b32 LDS writes.
    #pragma unroll 4
    for (int k = 0; k < 128; k += 2) {
        const unsigned int lo = f2bf(W1[k * D_HID + tid]);
        const unsigned int hi = f2bf(W1[(k + 1) * D_HID + tid]);
        *(unsigned int*)&w1s[tid * W1S + k] = lo | (hi << 16);
    }
    if (tid < D_HID) b1s[tid] = b1[tid];

    // ---- loop-invariant registers: W2 [n=256][t=16] -> w2f frags, b2 ----
    bf16x8 w2f[8];
    #pragma unroll
    for (int kc2 = 0; kc2 < 8; ++kc2) {
        u16x8 t;
        #pragma unroll
        for (int j = 0; j < 8; ++j)
            t[j] = f2bf(W2[(kc2 * 32 + q * 8 + j) * K_CL + c]);
        w2f[kc2] = __builtin_bit_cast(bf16x8, t);
    }
    const float b2v = b2[c];
    __syncthreads();

    unsigned short* const chA = &chbuf[wv][0][0];
    unsigned short* const chB = &chbuf[wv][1][0];

    const int wid     = blockIdx.x * 4 + wv;
    const int wstride = gridDim.x * 4;

    // ---- preload first tile's raw x (8 float4 = 32 VGPRs) ----
    float4 xraw[8];
    {
        const float* xr = x + (size_t)(wid * 16 + c) * D_INF + q * 8;
        #pragma unroll
        for (int j = 0; j < 8; ++j)
            xraw[j] = *(const float4*)(xr + (j >> 1) * 32 + (j & 1) * 4);
    }

    for (int tile = wid; tile < N_TILES; tile += wstride) {
        const int m0 = tile * 16;

        // ---- issue NEXT tile's x loads first (latency overlapped) ----
        const int nxt = tile + wstride;
        float4 xnxt[8];
        if (nxt < N_TILES) {
            const float* xr = x + (size_t)(nxt * 16 + c) * D_INF + q * 8;
            #pragma unroll
            for (int j = 0; j < 8; ++j)
                xnxt[j] = *(const float4*)(xr + (j >> 1) * 32 + (j & 1) * 4);
        }

        // ---- convert CURRENT tile's preloaded x -> A fragments ----
        bf16x8 afr[4];
        #pragma unroll
        for (int kc = 0; kc < 4; ++kc) {
            const float4 xa = xraw[kc * 2], xb = xraw[kc * 2 + 1];
            u16x8 af;
            af[0] = f2bf(xa.x); af[1] = f2bf(xa.y); af[2] = f2bf(xa.z); af[3] = f2bf(xa.w);
            af[4] = f2bf(xb.x); af[5] = f2bf(xb.y); af[6] = f2bf(xb.z); af[7] = f2bf(xb.w);
            afr[kc] = __builtin_bit_cast(bf16x8, af);
        }

        // ---- fused GEMM1 -> h chunk -> GEMM2, one nt-pair at a time ----
        f32x4 acc2 = (f32x4){0.f, 0.f, 0.f, 0.f};
        #pragma unroll
        for (int kc2 = 0; kc2 < 8; ++kc2) {
            unsigned short* const cb = (kc2 & 1) ? chB : chA;
            #pragma unroll
            for (int half = 0; half < 2; ++half) {
                const int nt = kc2 * 2 + half;
                f32x4 a1 = (f32x4){0.f, 0.f, 0.f, 0.f};
                #pragma unroll
                for (int kc = 0; kc < 4; ++kc) {
                    const bf16x8 bf =
                        *(const bf16x8*)&w1s[(nt * 16 + c) * W1S + kc * 32 + q * 8];
                    a1 = __builtin_amdgcn_mfma_f32_16x16x32_bf16(afr[kc], bf, a1, 0, 0, 0);
                }
                const float bv = b1s[nt * 16 + c];
                #pragma unroll
                for (int r = 0; r < 4; ++r)
                    cb[(4 * q + r) * CHS + half * 16 + c] =
                        f2bf(fmaxf(a1[r] + bv, 0.f));
            }
            const bf16x8 a2 = *(const bf16x8*)&cb[c * CHS + q * 8];
            acc2 = __builtin_amdgcn_mfma_f32_16x16x32_bf16(a2, w2f[kc2], acc2, 0, 0, 0);
        }

        // ---- softmax per row m = 4q+r across 16 c-lanes; dual store ----
        #pragma unroll
        for (int r = 0; r < 4; ++r) {
            const float l = acc2[r] + b2v;
            float mx = l;
            mx = fmaxf(mx, __shfl_xor(mx, 1));
            mx = fmaxf(mx, __shfl_xor(mx, 2));
            mx = fmaxf(mx, __shfl_xor(mx, 4));
            mx = fmaxf(mx, __shfl_xor(mx, 8));
            const float e = __expf(l - mx);
            float sm = e;
            sm += __shfl_xor(sm, 1);
            sm += __shfl_xor(sm, 2);
            sm += __shfl_xor(sm, 4);
            sm += __shfl_xor(sm, 8);
            const float p = e / sm;
            const size_t o = (size_t)(m0 + 4 * q + r) * K_CL + c;
            C[o]  = p;
            // fp8 e4m3 copy for the edge gather (native cvt, RNE)
            C8[o] = (unsigned char)
                (__builtin_amdgcn_cvt_pk_fp8_f32(p, p, 0, false) & 0xff);
        }

        // ---- rotate prefetched x into place ----
        if (nxt < N_TILES) {
            #pragma unroll
            for (int j = 0; j < 8; ++j) xraw[j] = xnxt[j];
        }
    }
}

// ---------------------------------------------------------------------------
// Edge reduction (R4 gather core, at the measured scattered-request floor:
// ~0.28 req/cyc/CU, invariant across R1-R4 probes of depth/occupancy/L1
// scope/request width). R5: finalize folded in via integer ticket -- last
// block reduces the 3125 partials and writes the loss. Agent-scope
// stores/loads for partials (per-XCD L2s are not coherent; the poison fill
// may have left stale lines in the reader's L2). R1 showed the CONTENDED
// fp32 atomic costs ~15us; one int atomicAdd per block, spread over block
// completions, is ~1us.
// ---------------------------------------------------------------------------
__global__ __launch_bounds__(256, 5) void edge_kernel(
    const int* __restrict__ ei, const unsigned char* __restrict__ C8,
    float* __restrict__ partials, unsigned int* __restrict__ ticket,
    float* __restrict__ out)
{
    __shared__ float red[4];
    __shared__ unsigned int is_last;
    const int tid  = threadIdx.x;
    const int lane = tid & 63;
    const int wv   = tid >> 6;
    const int base = (blockIdx.x * 4 + wv) * 256;

    // coalesced index loads: 4 edges per lane, no broadcast needed
    int u[4], v[4];
    #pragma unroll
    for (int j = 0; j < 4; ++j) {
        u[j] = ei[base + j * 64 + lane];
        v[j] = ei[N_EDGES + base + j * 64 + lane];
    }

    // 8 independent 16B gathers, all in flight together (32 VGPRs)
    u32x4 A[4], B[4];
    #pragma unroll
    for (int j = 0; j < 4; ++j) {
        A[j] = *(const u32x4*)(C8 + (size_t)u[j] * 16);
        B[j] = *(const u32x4*)(C8 + (size_t)v[j] * 16);
    }

    float s0 = 0.f, s1 = 0.f, s2 = 0.f, s3 = 0.f;
    #pragma unroll
    for (int j = 0; j < 4; ++j) {
        float t = 0.f;
        #pragma unroll
        for (int d = 0; d < 4; ++d) {
            const f32x2 a0 = __builtin_amdgcn_cvt_pk_f32_fp8(A[j][d], false);
            const f32x2 a1 = __builtin_amdgcn_cvt_pk_f32_fp8(A[j][d], true);
            const f32x2 b0 = __builtin_amdgcn_cvt_pk_f32_fp8(B[j][d], false);
            const f32x2 b1 = __builtin_amdgcn_cvt_pk_f32_fp8(B[j][d], true);
            t = fmaf(a0[0], b0[0], t);
            t = fmaf(a0[1], b0[1], t);
            t = fmaf(a1[0], b1[0], t);
            t = fmaf(a1[1], b1[1], t);
        }
        if (j == 0) s0 = t; else if (j == 1) s1 = t;
        else if (j == 2) s2 = t; else s3 = t;
    }
    float s = (s0 + s1) + (s2 + s3);

    s += __shfl_xor(s, 1);
    s += __shfl_xor(s, 2);
    s += __shfl_xor(s, 4);
    s += __shfl_xor(s, 8);
    s += __shfl_xor(s, 16);
    s += __shfl_xor(s, 32);
    if (lane == 0) red[wv] = s;
    __syncthreads();
    if (tid == 0) {
        const float bs = red[0] + red[1] + red[2] + red[3];
        __hip_atomic_store(&partials[blockIdx.x], bs, __ATOMIC_RELAXED,
                           __HIP_MEMORY_SCOPE_AGENT);
        __threadfence();
        const unsigned int old = atomicAdd(ticket, 1u);
        is_last = (old == (unsigned int)(EDGE_BLOCKS - 1)) ? 1u : 0u;
    }
    __syncthreads();

    if (is_last) {
        float t = 0.f;
        for (int i = tid; i < EDGE_BLOCKS; i += 256)
            t += __hip_atomic_load(&partials[i], __ATOMIC_RELAXED,
                                   __HIP_MEMORY_SCOPE_AGENT);
        t += __shfl_xor(t, 1);
        t += __shfl_xor(t, 2);
        t += __shfl_xor(t, 4);
        t += __shfl_xor(t, 8);
        t += __shfl_xor(t, 16);
        t += __shfl_xor(t, 32);
        if (lane == 0) red[wv] = t;
        __syncthreads();
        if (tid == 0)
            out[(size_t)N_NODES * K_CL] =
                -(red[0] + red[1] + red[2] + red[3]) / (float)N_EDGES;
    }
}

// ---------------------------------------------------------------------------
extern "C" void kernel_launch(void* const* d_in, const int* in_sizes, int n_in,
                              void* d_out, int out_size, void* d_ws, size_t ws_size,
                              hipStream_t stream) {
    const float* x  = (const float*)d_in[0];
    const int*   ei = (const int*)  d_in[1];
    const float* W1 = (const float*)d_in[2];
    const float* b1 = (const float*)d_in[3];
    const float* W2 = (const float*)d_in[4];
    const float* b2 = (const float*)d_in[5];
    float* out = (float*)d_out;

    // ws: C8 fp8 [100000*16] @0 (1.6 MB), partials f32 @1600000 (12.5 KB),
    //     ticket u32 @1612500
    unsigned char* C8       = (unsigned char*)d_ws;
    float*         partials = (float*)((char*)d_ws + 1600000);
    unsigned int*  ticket   = (unsigned int*)((char*)d_ws + 1612500);

    mlp_kernel<<<512, 256, 0, stream>>>(x, W1, b1, W2, b2, out, C8, ticket);
    edge_kernel<<<EDGE_BLOCKS, 256, 0, stream>>>(ei, C8, partials, ticket, out);
}

// Round 6
// 158.381 us; speedup vs baseline: 1.4344x; 1.4344x over previous
//
#include <hip/hip_runtime.h>

#define N_NODES 100000
#define D_INF   128
#define D_HID   256
#define K_CL    16
#define N_PAIRS (N_NODES / 32)       // 3125 pairs of 16-node tiles, exact
#define N_EDGES 3200000
#define EDGE_BLOCKS (N_EDGES / 1024) // 3125: 4 waves x 256 edges

typedef __attribute__((ext_vector_type(8))) __bf16  bf16x8;
typedef __attribute__((ext_vector_type(8))) unsigned short u16x8;
typedef __attribute__((ext_vector_type(4))) float   f32x4;
typedef __attribute__((ext_vector_type(2))) float   f32x2;
typedef __attribute__((ext_vector_type(4))) unsigned int u32x4;

__device__ __forceinline__ unsigned short f2bf(float f) {
    unsigned int u = __builtin_bit_cast(unsigned int, f);
    u += 0x7fffu + ((u >> 16) & 1u);          // RNE
    return (unsigned short)(u >> 16);
}

// ---------------------------------------------------------------------------
// Fused MLP. R5's prep-fold kept (W1/W2 converted in-block; prep kernel
// gone). R6 change: one wave = one 32-node PAIR of 16-row M-tiles, so each
// W1 fragment ds_read_b128 feeds TWO MFMAs -- GEMM1 LDS reads halved (the
// largest on-chip term, ~12us kernel-wide at 1 tile/wave).
// h round-trip: chA = tile0, chB = tile1, single-buffered per tile --
// same-wave DS ordering (write chunk -> read chunk in program order) is
// exactly the pattern the 1-tile version already relied on.
// NO device/agent fences anywhere: R5 showed per-block __threadfence()
// invalidates the XCD L2 and tripled the edge kernel (227us total).
// ---------------------------------------------------------------------------
#define W1S 136      // LDS row stride (bf16) for W1T
#define CHS 40       // LDS row stride (bf16) for h chunk

__global__ __launch_bounds__(256, 2) void mlp_kernel(
    const float* __restrict__ x, const float* __restrict__ W1,
    const float* __restrict__ b1, const float* __restrict__ W2,
    const float* __restrict__ b2, float* __restrict__ C,
    unsigned char* __restrict__ C8)
{
    __shared__ unsigned short w1s[256 * W1S];          // 69,632 B
    __shared__ unsigned short chbuf[4][2][16 * CHS];   // 10,240 B
    __shared__ float b1s[D_HID];                       //  1,024 B -> 80,896

    const int tid  = threadIdx.x;
    const int wv   = tid >> 6;
    const int lane = tid & 63;
    const int c    = lane & 15;
    const int q    = lane >> 4;

    // ---- stage W1 [k=128][n=256] f32 -> w1s[n][k] bf16 (transposed) ----
    #pragma unroll 4
    for (int k = 0; k < 128; k += 2) {
        const unsigned int lo = f2bf(W1[k * D_HID + tid]);
        const unsigned int hi = f2bf(W1[(k + 1) * D_HID + tid]);
        *(unsigned int*)&w1s[tid * W1S + k] = lo | (hi << 16);
    }
    if (tid < D_HID) b1s[tid] = b1[tid];

    // ---- loop-invariant registers: W2 [n=256][t=16] -> w2f frags, b2 ----
    bf16x8 w2f[8];
    #pragma unroll
    for (int kc2 = 0; kc2 < 8; ++kc2) {
        u16x8 t;
        #pragma unroll
        for (int j = 0; j < 8; ++j)
            t[j] = f2bf(W2[(kc2 * 32 + q * 8 + j) * K_CL + c]);
        w2f[kc2] = __builtin_bit_cast(bf16x8, t);
    }
    const float b2v = b2[c];
    __syncthreads();

    unsigned short* const chA = &chbuf[wv][0][0];
    unsigned short* const chB = &chbuf[wv][1][0];

    const int wid     = blockIdx.x * 4 + wv;
    const int wstride = gridDim.x * 4;

    // ---- preload first pair's raw x (16 float4) ----
    float4 xraw[16];
    {
        const float* xr0 = x + (size_t)(wid * 32 + c)      * D_INF + q * 8;
        const float* xr1 = x + (size_t)(wid * 32 + 16 + c) * D_INF + q * 8;
        #pragma unroll
        for (int j = 0; j < 8; ++j) {
            xraw[j]     = *(const float4*)(xr0 + (j >> 1) * 32 + (j & 1) * 4);
            xraw[8 + j] = *(const float4*)(xr1 + (j >> 1) * 32 + (j & 1) * 4);
        }
    }

    for (int pair = wid; pair < N_PAIRS; pair += wstride) {
        const int m0 = pair * 32;

        // ---- convert preloaded x -> A fragments for both tiles ----
        bf16x8 afr0[4], afr1[4];
        #pragma unroll
        for (int kc = 0; kc < 4; ++kc) {
            const float4 xa = xraw[kc * 2],     xb = xraw[kc * 2 + 1];
            const float4 ya = xraw[8 + kc * 2], yb = xraw[8 + kc * 2 + 1];
            u16x8 af, ag;
            af[0] = f2bf(xa.x); af[1] = f2bf(xa.y); af[2] = f2bf(xa.z); af[3] = f2bf(xa.w);
            af[4] = f2bf(xb.x); af[5] = f2bf(xb.y); af[6] = f2bf(xb.z); af[7] = f2bf(xb.w);
            ag[0] = f2bf(ya.x); ag[1] = f2bf(ya.y); ag[2] = f2bf(ya.z); ag[3] = f2bf(ya.w);
            ag[4] = f2bf(yb.x); ag[5] = f2bf(yb.y); ag[6] = f2bf(yb.z); ag[7] = f2bf(yb.w);
            afr0[kc] = __builtin_bit_cast(bf16x8, af);
            afr1[kc] = __builtin_bit_cast(bf16x8, ag);
        }

        // ---- issue NEXT pair's x loads (xraw regs just freed) ----
        const int nxt = pair + wstride;
        if (nxt < N_PAIRS) {
            const float* xr0 = x + (size_t)(nxt * 32 + c)      * D_INF + q * 8;
            const float* xr1 = x + (size_t)(nxt * 32 + 16 + c) * D_INF + q * 8;
            #pragma unroll
            for (int j = 0; j < 8; ++j) {
                xraw[j]     = *(const float4*)(xr0 + (j >> 1) * 32 + (j & 1) * 4);
                xraw[8 + j] = *(const float4*)(xr1 + (j >> 1) * 32 + (j & 1) * 4);
            }
        }

        // ---- fused GEMM1 -> h chunks -> GEMM2, both tiles per bf read ----
        f32x4 acc2a = (f32x4){0.f, 0.f, 0.f, 0.f};
        f32x4 acc2b = (f32x4){0.f, 0.f, 0.f, 0.f};
        #pragma unroll
        for (int kc2 = 0; kc2 < 8; ++kc2) {
            #pragma unroll
            for (int half = 0; half < 2; ++half) {
                const int nt = kc2 * 2 + half;
                f32x4 a1a = (f32x4){0.f, 0.f, 0.f, 0.f};
                f32x4 a1b = (f32x4){0.f, 0.f, 0.f, 0.f};
                #pragma unroll
                for (int kc = 0; kc < 4; ++kc) {
                    const bf16x8 bf =
                        *(const bf16x8*)&w1s[(nt * 16 + c) * W1S + kc * 32 + q * 8];
                    a1a = __builtin_amdgcn_mfma_f32_16x16x32_bf16(afr0[kc], bf, a1a, 0, 0, 0);
                    a1b = __builtin_amdgcn_mfma_f32_16x16x32_bf16(afr1[kc], bf, a1b, 0, 0, 0);
                }
                const float bv = b1s[nt * 16 + c];
                #pragma unroll
                for (int r = 0; r < 4; ++r) {
                    chA[(4 * q + r) * CHS + half * 16 + c] =
                        f2bf(fmaxf(a1a[r] + bv, 0.f));
                    chB[(4 * q + r) * CHS + half * 16 + c] =
                        f2bf(fmaxf(a1b[r] + bv, 0.f));
                }
            }
            const bf16x8 a2a = *(const bf16x8*)&chA[c * CHS + q * 8];
            const bf16x8 a2b = *(const bf16x8*)&chB[c * CHS + q * 8];
            acc2a = __builtin_amdgcn_mfma_f32_16x16x32_bf16(a2a, w2f[kc2], acc2a, 0, 0, 0);
            acc2b = __builtin_amdgcn_mfma_f32_16x16x32_bf16(a2b, w2f[kc2], acc2b, 0, 0, 0);
        }

        // ---- softmax per row across 16 c-lanes; dual store; both tiles ----
        #pragma unroll
        for (int t2 = 0; t2 < 2; ++t2) {
            const f32x4 acc2 = t2 ? acc2b : acc2a;
            const int mb = m0 + t2 * 16;
            #pragma unroll
            for (int r = 0; r < 4; ++r) {
                const float l = acc2[r] + b2v;
                float mx = l;
                mx = fmaxf(mx, __shfl_xor(mx, 1));
                mx = fmaxf(mx, __shfl_xor(mx, 2));
                mx = fmaxf(mx, __shfl_xor(mx, 4));
                mx = fmaxf(mx, __shfl_xor(mx, 8));
                const float e = __expf(l - mx);
                float sm = e;
                sm += __shfl_xor(sm, 1);
                sm += __shfl_xor(sm, 2);
                sm += __shfl_xor(sm, 4);
                sm += __shfl_xor(sm, 8);
                const float p = e / sm;
                const size_t o = (size_t)(mb + 4 * q + r) * K_CL + c;
                C[o]  = p;
                C8[o] = (unsigned char)
                    (__builtin_amdgcn_cvt_pk_fp8_f32(p, p, 0, false) & 0xff);
            }
        }
    }
}

// ---------------------------------------------------------------------------
// Edge reduction (R4 verbatim -- the measured-safe version, ~36us at the
// scattered-request service floor of ~0.28 req/cyc/CU). fp8 rows: one
// dwordx4 lane-address per edge-side; unpack via v_cvt_pk_f32_fp8.
// Plain partials store + separate finalize kernel; NO fences/atomics in
// here (R5's per-block agent fence invalidated L2 -> 3.5x regression).
// ---------------------------------------------------------------------------
__global__ __launch_bounds__(256, 5) void edge_kernel(
    const int* __restrict__ ei, const unsigned char* __restrict__ C8,
    float* __restrict__ partials)
{
    __shared__ float red[4];
    const int tid  = threadIdx.x;
    const int lane = tid & 63;
    const int wv   = tid >> 6;
    const int base = (blockIdx.x * 4 + wv) * 256;

    // coalesced index loads: 4 edges per lane, no broadcast needed
    int u[4], v[4];
    #pragma unroll
    for (int j = 0; j < 4; ++j) {
        u[j] = ei[base + j * 64 + lane];
        v[j] = ei[N_EDGES + base + j * 64 + lane];
    }

    // 8 independent 16B gathers, all in flight together (32 VGPRs)
    u32x4 A[4], B[4];
    #pragma unroll
    for (int j = 0; j < 4; ++j) {
        A[j] = *(const u32x4*)(C8 + (size_t)u[j] * 16);
        B[j] = *(const u32x4*)(C8 + (size_t)v[j] * 16);
    }

    float s0 = 0.f, s1 = 0.f, s2 = 0.f, s3 = 0.f;
    #pragma unroll
    for (int j = 0; j < 4; ++j) {
        float t = 0.f;
        #pragma unroll
        for (int d = 0; d < 4; ++d) {
            const f32x2 a0 = __builtin_amdgcn_cvt_pk_f32_fp8(A[j][d], false);
            const f32x2 a1 = __builtin_amdgcn_cvt_pk_f32_fp8(A[j][d], true);
            const f32x2 b0 = __builtin_amdgcn_cvt_pk_f32_fp8(B[j][d], false);
            const f32x2 b1 = __builtin_amdgcn_cvt_pk_f32_fp8(B[j][d], true);
            t = fmaf(a0[0], b0[0], t);
            t = fmaf(a0[1], b0[1], t);
            t = fmaf(a1[0], b1[0], t);
            t = fmaf(a1[1], b1[1], t);
        }
        if (j == 0) s0 = t; else if (j == 1) s1 = t;
        else if (j == 2) s2 = t; else s3 = t;
    }
    float s = (s0 + s1) + (s2 + s3);

    s += __shfl_xor(s, 1);
    s += __shfl_xor(s, 2);
    s += __shfl_xor(s, 4);
    s += __shfl_xor(s, 8);
    s += __shfl_xor(s, 16);
    s += __shfl_xor(s, 32);
    if (lane == 0) red[wv] = s;
    __syncthreads();
    if (tid == 0) partials[blockIdx.x] = red[0] + red[1] + red[2] + red[3];
}

// ---------------------------------------------------------------------------
// Finalize: reduce 3125 block partials, write -sum/E.
// ---------------------------------------------------------------------------
__global__ __launch_bounds__(256) void finalize_kernel(
    const float* __restrict__ partials, float* __restrict__ out)
{
    __shared__ float red[4];
    const int tid = threadIdx.x;
    float s = 0.f;
    for (int i = tid; i < EDGE_BLOCKS; i += 256) s += partials[i];
    s += __shfl_xor(s, 1);
    s += __shfl_xor(s, 2);
    s += __shfl_xor(s, 4);
    s += __shfl_xor(s, 8);
    s += __shfl_xor(s, 16);
    s += __shfl_xor(s, 32);
    if ((tid & 63) == 0) red[tid >> 6] = s;
    __syncthreads();
    if (tid == 0)
        out[(size_t)N_NODES * K_CL] =
            -(red[0] + red[1] + red[2] + red[3]) / (float)N_EDGES;
}

// ---------------------------------------------------------------------------
extern "C" void kernel_launch(void* const* d_in, const int* in_sizes, int n_in,
                              void* d_out, int out_size, void* d_ws, size_t ws_size,
                              hipStream_t stream) {
    const float* x  = (const float*)d_in[0];
    const int*   ei = (const int*)  d_in[1];
    const float* W1 = (const float*)d_in[2];
    const float* b1 = (const float*)d_in[3];
    const float* W2 = (const float*)d_in[4];
    const float* b2 = (const float*)d_in[5];
    float* out = (float*)d_out;

    // ws: C8 fp8 [100000*16] @0 (1.6 MB), partials f32 @1600000 (12.5 KB)
    unsigned char* C8       = (unsigned char*)d_ws;
    float*         partials = (float*)((char*)d_ws + 1600000);

    mlp_kernel<<<512, 256, 0, stream>>>(x, W1, b1, W2, b2, out, C8);
    edge_kernel<<<EDGE_BLOCKS, 256, 0, stream>>>(ei, C8, partials);
    finalize_kernel<<<1, 256, 0, stream>>>(partials, out);
}

// Round 7
// 154.098 us; speedup vs baseline: 1.4743x; 1.0278x over previous
//
#include <hip/hip_runtime.h>

#define N_NODES 100000
#define D_INF   128
#define D_HID   256
#define K_CL    16
#define N_TILES (N_NODES / 16)       // 6250, exact
#define N_EDGES 3200000
#define EDGE_BLOCKS (N_EDGES / 1024) // 3125: 4 waves x 256 edges

typedef __attribute__((ext_vector_type(8))) __bf16  bf16x8;
typedef __attribute__((ext_vector_type(8))) unsigned short u16x8;
typedef __attribute__((ext_vector_type(4))) float   f32x4;
typedef __attribute__((ext_vector_type(2))) float   f32x2;
typedef __attribute__((ext_vector_type(4))) unsigned int u32x4;

__device__ __forceinline__ unsigned short f2bf(float f) {
    unsigned int u = __builtin_bit_cast(unsigned int, f);
    u += 0x7fffu + ((u >> 16) & 1u);          // RNE
    return (unsigned short)(u >> 16);
}

// ---------------------------------------------------------------------------
// Prep: W1 [128][256] f32 -> W1T [256][128] bf16 ; W2 [256][16] f32 -> W2T
// [16][256] bf16. Writes coalesced. Kept as a separate kernel: folding it
// into mlp (R5/R6) costs 512x redundant f32 W1 reads (+32MB L2 traffic) for
// only one saved graph node -- measured net-negative.
// ---------------------------------------------------------------------------
__global__ void prep_kernel(const float* __restrict__ W1,
                            const float* __restrict__ W2,
                            unsigned short* __restrict__ w1t,
                            unsigned short* __restrict__ w2t)
{
    const int i = blockIdx.x * 256 + threadIdx.x;
    if (i < D_INF * D_HID) {                  // w1t[n][k] = W1[k][n]
        const int n = i >> 7, k = i & 127;
        w1t[i] = f2bf(W1[k * D_HID + n]);
    }
    if (i < D_HID * K_CL) {                   // w2t[t][n] = W2[n][t]
        const int t = i >> 8, n = i & 255;
        w2t[i] = f2bf(W2[n * K_CL + t]);
    }
}

// ---------------------------------------------------------------------------
// Fused MLP (R4 verbatim -- measured best). MFMA 16x16x32 bf16, 4 waves per
// block, wave = ONE 16-node tile (pair-tiling regressed: doubles xraw VGPRs
// and forces prefetch after converts, losing issue-first latency hiding).
// W1T staged in LDS; h chunk round-trips per-wave LDS (in-wave DS order);
// next tile's 8 float4 x loads issued at the TOP of each iteration.
// fp8 e4m3 loss-path copy of C (R4): halves edge gather addresses.
// ---------------------------------------------------------------------------
#define W1S 136      // LDS row stride (bf16) for W1T
#define CHS 40       // LDS row stride (bf16) for h chunk

__global__ __launch_bounds__(256, 2) void mlp_kernel(
    const float* __restrict__ x, const unsigned short* __restrict__ W1T,
    const float* __restrict__ b1, const unsigned short* __restrict__ W2T,
    const float* __restrict__ b2, float* __restrict__ C,
    unsigned char* __restrict__ C8)
{
    __shared__ unsigned short w1s[256 * W1S];          // 69,632 B
    __shared__ unsigned short chbuf[4][2][16 * CHS];   // 10,240 B
    __shared__ float b1s[D_HID];                       //  1,024 B -> 80,896

    const int tid  = threadIdx.x;
    const int wv   = tid >> 6;
    const int lane = tid & 63;
    const int c    = lane & 15;
    const int q    = lane >> 4;

    // ---- stage W1T into LDS (coalesced uint4 reads, b128 LDS writes) ----
    #pragma unroll
    for (int it = 0; it < 16; ++it) {
        const int idx = it * 256 + tid;        // 4096 uint4 chunks
        const int row = idx >> 4, ch = idx & 15;
        const uint4 v = ((const uint4*)W1T)[idx];
        *(uint4*)&w1s[row * W1S + ch * 8] = v;
    }
    if (tid < D_HID) b1s[tid] = b1[tid];

    // ---- loop-invariant registers: W2T fragments (32 VGPRs), b2 ----
    bf16x8 w2f[8];
    #pragma unroll
    for (int kc2 = 0; kc2 < 8; ++kc2)
        w2f[kc2] = *(const bf16x8*)(W2T + (size_t)c * D_HID + kc2 * 32 + q * 8);
    const float b2v = b2[c];
    __syncthreads();

    unsigned short* const chA = &chbuf[wv][0][0];
    unsigned short* const chB = &chbuf[wv][1][0];

    const int wid     = blockIdx.x * 4 + wv;
    const int wstride = gridDim.x * 4;

    // ---- preload first tile's raw x (8 float4 = 32 VGPRs) ----
    float4 xraw[8];
    {
        const float* xr = x + (size_t)(wid * 16 + c) * D_INF + q * 8;
        #pragma unroll
        for (int j = 0; j < 8; ++j)
            xraw[j] = *(const float4*)(xr + (j >> 1) * 32 + (j & 1) * 4);
    }

    for (int tile = wid; tile < N_TILES; tile += wstride) {
        const int m0 = tile * 16;

        // ---- issue NEXT tile's x loads first (latency overlapped) ----
        const int nxt = tile + wstride;
        float4 xnxt[8];
        if (nxt < N_TILES) {
            const float* xr = x + (size_t)(nxt * 16 + c) * D_INF + q * 8;
            #pragma unroll
            for (int j = 0; j < 8; ++j)
                xnxt[j] = *(const float4*)(xr + (j >> 1) * 32 + (j & 1) * 4);
        }

        // ---- convert CURRENT tile's preloaded x -> A fragments ----
        bf16x8 afr[4];
        #pragma unroll
        for (int kc = 0; kc < 4; ++kc) {
            const float4 xa = xraw[kc * 2], xb = xraw[kc * 2 + 1];
            u16x8 af;
            af[0] = f2bf(xa.x); af[1] = f2bf(xa.y); af[2] = f2bf(xa.z); af[3] = f2bf(xa.w);
            af[4] = f2bf(xb.x); af[5] = f2bf(xb.y); af[6] = f2bf(xb.z); af[7] = f2bf(xb.w);
            afr[kc] = __builtin_bit_cast(bf16x8, af);
        }

        // ---- fused GEMM1 -> h chunk -> GEMM2, one nt-pair at a time ----
        f32x4 acc2 = (f32x4){0.f, 0.f, 0.f, 0.f};
        #pragma unroll
        for (int kc2 = 0; kc2 < 8; ++kc2) {
            unsigned short* const cb = (kc2 & 1) ? chB : chA;
            #pragma unroll
            for (int half = 0; half < 2; ++half) {
                const int nt = kc2 * 2 + half;
                f32x4 a1 = (f32x4){0.f, 0.f, 0.f, 0.f};
                #pragma unroll
                for (int kc = 0; kc < 4; ++kc) {
                    const bf16x8 bf =
                        *(const bf16x8*)&w1s[(nt * 16 + c) * W1S + kc * 32 + q * 8];
                    a1 = __builtin_amdgcn_mfma_f32_16x16x32_bf16(afr[kc], bf, a1, 0, 0, 0);
                }
                const float bv = b1s[nt * 16 + c];
                #pragma unroll
                for (int r = 0; r < 4; ++r)
                    cb[(4 * q + r) * CHS + half * 16 + c] =
                        f2bf(fmaxf(a1[r] + bv, 0.f));
            }
            const bf16x8 a2 = *(const bf16x8*)&cb[c * CHS + q * 8];
            acc2 = __builtin_amdgcn_mfma_f32_16x16x32_bf16(a2, w2f[kc2], acc2, 0, 0, 0);
        }

        // ---- softmax per row m = 4q+r across 16 c-lanes; dual store ----
        #pragma unroll
        for (int r = 0; r < 4; ++r) {
            const float l = acc2[r] + b2v;
            float mx = l;
            mx = fmaxf(mx, __shfl_xor(mx, 1));
            mx = fmaxf(mx, __shfl_xor(mx, 2));
            mx = fmaxf(mx, __shfl_xor(mx, 4));
            mx = fmaxf(mx, __shfl_xor(mx, 8));
            const float e = __expf(l - mx);
            float sm = e;
            sm += __shfl_xor(sm, 1);
            sm += __shfl_xor(sm, 2);
            sm += __shfl_xor(sm, 4);
            sm += __shfl_xor(sm, 8);
            const float p = e / sm;
            const size_t o = (size_t)(m0 + 4 * q + r) * K_CL + c;
            C[o]  = p;
            // fp8 e4m3 copy for the edge gather (native cvt, RNE)
            C8[o] = (unsigned char)
                (__builtin_amdgcn_cvt_pk_fp8_f32(p, p, 0, false) & 0xff);
        }

        // ---- rotate prefetched x into place ----
        if (nxt < N_TILES) {
            #pragma unroll
            for (int j = 0; j < 8; ++j) xraw[j] = xnxt[j];
        }
    }
}

// ---------------------------------------------------------------------------
// Edge reduction (R4 verbatim). fp8 rows: one dwordx4 lane-address per
// edge-side; unpack via v_cvt_pk_f32_fp8. At the measured scattered-request
// service floor (~0.28 req/cyc/CU), invariant across R1-R4 probes of
// window depth / occupancy / L1 scope / request width. Plain partials
// store + separate finalize; NO fences or single-address atomics (R5's
// per-block agent fence invalidated L2 -> 3.5x regression; R1's contended
// fp32 atomic cost +15us).
// ---------------------------------------------------------------------------
__global__ __launch_bounds__(256, 5) void edge_kernel(
    const int* __restrict__ ei, const unsigned char* __restrict__ C8,
    float* __restrict__ partials)
{
    __shared__ float red[4];
    const int tid  = threadIdx.x;
    const int lane = tid & 63;
    const int wv   = tid >> 6;
    const int base = (blockIdx.x * 4 + wv) * 256;

    // coalesced index loads: 4 edges per lane, no broadcast needed
    int u[4], v[4];
    #pragma unroll
    for (int j = 0; j < 4; ++j) {
        u[j] = ei[base + j * 64 + lane];
        v[j] = ei[N_EDGES + base + j * 64 + lane];
    }

    // 8 independent 16B gathers, all in flight together (32 VGPRs)
    u32x4 A[4], B[4];
    #pragma unroll
    for (int j = 0; j < 4; ++j) {
        A[j] = *(const u32x4*)(C8 + (size_t)u[j] * 16);
        B[j] = *(const u32x4*)(C8 + (size_t)v[j] * 16);
    }

    float s0 = 0.f, s1 = 0.f, s2 = 0.f, s3 = 0.f;
    #pragma unroll
    for (int j = 0; j < 4; ++j) {
        float t = 0.f;
        #pragma unroll
        for (int d = 0; d < 4; ++d) {
            const f32x2 a0 = __builtin_amdgcn_cvt_pk_f32_fp8(A[j][d], false);
            const f32x2 a1 = __builtin_amdgcn_cvt_pk_f32_fp8(A[j][d], true);
            const f32x2 b0 = __builtin_amdgcn_cvt_pk_f32_fp8(B[j][d], false);
            const f32x2 b1 = __builtin_amdgcn_cvt_pk_f32_fp8(B[j][d], true);
            t = fmaf(a0[0], b0[0], t);
            t = fmaf(a0[1], b0[1], t);
            t = fmaf(a1[0], b1[0], t);
            t = fmaf(a1[1], b1[1], t);
        }
        if (j == 0) s0 = t; else if (j == 1) s1 = t;
        else if (j == 2) s2 = t; else s3 = t;
    }
    float s = (s0 + s1) + (s2 + s3);

    s += __shfl_xor(s, 1);
    s += __shfl_xor(s, 2);
    s += __shfl_xor(s, 4);
    s += __shfl_xor(s, 8);
    s += __shfl_xor(s, 16);
    s += __shfl_xor(s, 32);
    if (lane == 0) red[wv] = s;
    __syncthreads();
    if (tid == 0) partials[blockIdx.x] = red[0] + red[1] + red[2] + red[3];
}

// ---------------------------------------------------------------------------
// Finalize: reduce 3125 block partials, write -sum/E.
// ---------------------------------------------------------------------------
__global__ __launch_bounds__(256) void finalize_kernel(
    const float* __restrict__ partials, float* __restrict__ out)
{
    __shared__ float red[4];
    const int tid = threadIdx.x;
    float s = 0.f;
    for (int i = tid; i < EDGE_BLOCKS; i += 256) s += partials[i];
    s += __shfl_xor(s, 1);
    s += __shfl_xor(s, 2);
    s += __shfl_xor(s, 4);
    s += __shfl_xor(s, 8);
    s += __shfl_xor(s, 16);
    s += __shfl_xor(s, 32);
    if ((tid & 63) == 0) red[tid >> 6] = s;
    __syncthreads();
    if (tid == 0)
        out[(size_t)N_NODES * K_CL] =
            -(red[0] + red[1] + red[2] + red[3]) / (float)N_EDGES;
}

// ---------------------------------------------------------------------------
extern "C" void kernel_launch(void* const* d_in, const int* in_sizes, int n_in,
                              void* d_out, int out_size, void* d_ws, size_t ws_size,
                              hipStream_t stream) {
    const float* x  = (const float*)d_in[0];
    const int*   ei = (const int*)  d_in[1];
    const float* W1 = (const float*)d_in[2];
    const float* b1 = (const float*)d_in[3];
    const float* W2 = (const float*)d_in[4];
    const float* b2 = (const float*)d_in[5];
    float* out = (float*)d_out;

    // ws: W1T bf16 @0 (64 KB), W2T bf16 @65536 (8 KB),
    //     C8 fp8 [100000*16] @73760 (1.6 MB), partials f32 @1673760 (12.5 KB)
    unsigned short* w1t      = (unsigned short*)d_ws;
    unsigned short* w2t      = (unsigned short*)((char*)d_ws + 65536);
    unsigned char*  C8       = (unsigned char*)((char*)d_ws + 73760);
    float*          partials = (float*)((char*)d_ws + 1673760);

    prep_kernel<<<128, 256, 0, stream>>>(W1, W2, w1t, w2t);
    mlp_kernel<<<512, 256, 0, stream>>>(x, w1t, b1, w2t, b2, out, C8);
    edge_kernel<<<EDGE_BLOCKS, 256, 0, stream>>>(ei, C8, partials);
    finalize_kernel<<<1, 256, 0, stream>>>(partials, out);
}